// Round 11
// baseline (2142.253 us; speedup 1.0000x reference)
//
#include <hip/hip_runtime.h>
#include <math.h>

// Bidirectional 10-layer tanh RNN, T=512 B=64 H=100, + sigmoid head.
// R11: (1) scan's hi/lo pack + global store moved AFTER the barrier (next
// step's shadow; it's fire-and-forget) + RTZ hi split (cheaper than RNE,
// lo absorbs the error). (2) layer-0 GEMM moved to the MFMA path too:
// x packed to hi/lo u32 [M][128] (K=100->128), W_ih0 split to [208][128]
// planes, ingemm_mfma templated over <NCHUNK, KPITCH>. xpk aliases pkB
// (consumed before pkB's first use at l=1). Scan core is R6's (banked).

#define T_LEN 512
#define BATCH 64
#define HID   100
#define M_TOT (T_LEN * BATCH)   // 32768
#define KPAD  224               // 7 chunks of 32 (layers 1..9)
#define KP0   128               // 4 chunks of 32 (layer 0)
#define NPAD  208               // 13 tiles of 16
#define WPLANE (NPAD * KPAD)    // 46592
#define W0PLANE (NPAD * KP0)    // 26624

typedef unsigned short ushort_t;
typedef unsigned int   uint_t;
typedef __attribute__((ext_vector_type(8))) __bf16 bf16x8;
typedef __attribute__((ext_vector_type(4))) float f32x4;
typedef __attribute__((ext_vector_type(8))) unsigned int uintx8;

// ---------------- helpers: bf16 splits ----------------
__device__ __forceinline__ unsigned bf16_rne(float v) {
    unsigned u = __float_as_uint(v);
    return (u + 0x7FFFu + ((u >> 16) & 1u)) >> 16;
}
// pack hi(RTZ) | lo(RNE of residual) << 16
__device__ __forceinline__ uint_t pack_hilo(float v) {
    unsigned u = __float_as_uint(v);
    float lo = v - __uint_as_float(u & 0xFFFF0000u);
    return (u >> 16) | (bf16_rne(lo) << 16);
}

// zero the pad columns (k = 200..223) of the 2 packed ping-pong arrays
__global__ __launch_bounds__(256) void zeropad_kernel(uint_t* a, uint_t* b)
{
    int i = blockIdx.x * 256 + threadIdx.x;      // M*24
    if (i >= M_TOT * 24) return;
    size_t off = (size_t)(i / 24) * KPAD + 200 + (i % 24);
    a[off] = 0; b[off] = 0;
}

// split ALL 9 layers' W_ih (fp32 [200][200]) into zero-padded bf16 hi/lo
// planes: wbuf + l*2*WPLANE = hi plane, + WPLANE = lo plane.
__global__ __launch_bounds__(256) void wsplit_all_kernel(
    const float* __restrict__ W_ih, ushort_t* __restrict__ wbuf)
{
    int i = blockIdx.x * 256 + threadIdx.x;      // 9*WPLANE
    if (i >= 9 * WPLANE) return;
    int l = i / WPLANE;
    int r = i - l * WPLANE;
    int n = r / KPAD, k = r - (r / KPAD) * KPAD;
    const float* W = W_ih + (size_t)l * 2 * 100 * 200;
    float v = (n < 200 && k < 200) ? W[n * 200 + k] : 0.f;
    unsigned hr = bf16_rne(v);
    float hv = __uint_as_float(hr << 16);
    unsigned lr = bf16_rne(v - hv);
    ushort_t* whi = wbuf + (size_t)l * 2 * WPLANE;
    whi[r] = (ushort_t)hr;
    whi[WPLANE + r] = (ushort_t)lr;
}

// split W_ih0 (fp32 [2][100][100] = [200][100]) into [NPAD][KP0] hi/lo planes
__global__ __launch_bounds__(256) void wsplit0_kernel(
    const float* __restrict__ W_ih0, ushort_t* __restrict__ w0buf)
{
    int i = blockIdx.x * 256 + threadIdx.x;      // NPAD*KP0
    if (i >= W0PLANE) return;
    int n = i >> 7, k = i & 127;
    float v = (n < 200 && k < 100) ? W_ih0[n * 100 + k] : 0.f;
    unsigned hr = bf16_rne(v);
    float hv = __uint_as_float(hr << 16);
    unsigned lr = bf16_rne(v - hv);
    w0buf[i] = (ushort_t)hr;
    w0buf[W0PLANE + i] = (ushort_t)lr;
}

// pack input x (fp32 [M][100]) into hi/lo u32 [M][KP0], k>=100 zero
__global__ __launch_bounds__(256) void xsplit_kernel(
    const float* __restrict__ x, uint_t* __restrict__ xpk)
{
    int i = blockIdx.x * 256 + threadIdx.x;      // M*KP0
    if (i >= M_TOT * KP0) return;
    int m = i >> 7, k = i & 127;
    float v = (k < 100) ? x[(size_t)m * 100 + k] : 0.f;
    xpk[i] = pack_hilo(v);
}

// ---------------- MFMA input GEMM ----------------
// In = packed u32 [M][KP] (hi | lo<<16); W = pre-split hi/lo planes [NPAD][KP].
// One wave per 16-row m-tile; A hi/lo frags unpacked once; loop 13 n-tiles x
// NC k-chunks x 3 MFMA (hh, hl, lh). Fragment layout: lane -> (row=lane&15,
// k=8*(lane>>4)+b); D: col=lane&15, row=(lane>>4)*4+reg.
template<int NC, int KP>
__global__ __launch_bounds__(256) void ingemm_mfma_kernel(
    const uint_t* __restrict__ in_pk,
    const ushort_t* __restrict__ w_hi,  const ushort_t* __restrict__ w_lo,
    const float* __restrict__ bih, const float* __restrict__ bhh,
    float* __restrict__ z)
{
    const int wv   = threadIdx.x >> 6;
    const int lane = threadIdx.x & 63;
    const int mt   = blockIdx.x * 4 + wv;     // m-tile 0..2047
    const int m0   = mt * 16;
    const int r16  = lane & 15;
    const int kg   = lane >> 4;
    const int kof  = kg * 8;

    // A fragments: NC k-chunks x {hi, lo}, unpacked from packed u32
    bf16x8 ah[NC], al[NC];
    const uint_t* arp = in_pk + (size_t)(m0 + r16) * KP + kof;
    #pragma unroll
    for (int c = 0; c < NC; ++c) {
        uintx8 p = *(const uintx8*)(arp + 32 * c);
        union { bf16x8 v; ushort_t u[8]; } hh, ll;
        #pragma unroll
        for (int i = 0; i < 8; ++i) {
            hh.u[i] = (ushort_t)(p[i] & 0xFFFFu);
            ll.u[i] = (ushort_t)(p[i] >> 16);
        }
        ah[c] = hh.v; al[c] = ll.v;
    }

    for (int nt = 0; nt < 13; ++nt) {
        const int n0 = nt * 16;
        const ushort_t* brh = w_hi + (size_t)(n0 + r16) * KP + kof;
        const ushort_t* brl = w_lo + (size_t)(n0 + r16) * KP + kof;
        f32x4 acc = {0.f, 0.f, 0.f, 0.f};
        #pragma unroll
        for (int c = 0; c < NC; ++c) {
            bf16x8 bh = *(const bf16x8*)(brh + 32 * c);
            bf16x8 bl = *(const bf16x8*)(brl + 32 * c);
            acc = __builtin_amdgcn_mfma_f32_16x16x32_bf16(ah[c], bh, acc, 0, 0, 0);
            acc = __builtin_amdgcn_mfma_f32_16x16x32_bf16(ah[c], bl, acc, 0, 0, 0);
            acc = __builtin_amdgcn_mfma_f32_16x16x32_bf16(al[c], bh, acc, 0, 0, 0);
        }
        const int n = n0 + r16;
        if (n < 200) {
            const int dir = (n >= 100) ? 1 : 0;
            const int h = n - dir * 100;
            const float bias = bih[n] + bhh[n];
            #pragma unroll
            for (int r = 0; r < 4; ++r) {
                const int m = m0 + kg * 4 + r;
                z[(size_t)dir * M_TOT * HID + (size_t)m * HID + h] = acc[r] + bias;
            }
        }
    }
}

// DPP helpers — guaranteed VALU lane exchange (no LDS).
__device__ __forceinline__ float dpp_qxor1(float x) {
    int i = __float_as_int(x);
    i = __builtin_amdgcn_update_dpp(0, i, 0xB1, 0xF, 0xF, false);
    return __int_as_float(i);
}
__device__ __forceinline__ float dpp_qxor2(float x) {
    int i = __float_as_int(x);
    i = __builtin_amdgcn_update_dpp(0, i, 0x4E, 0xF, 0xF, false);
    return __int_as_float(i);
}
__device__ __forceinline__ float dpp_hmir(float x) {  // lane ^ 7
    int i = __float_as_int(x);
    i = __builtin_amdgcn_update_dpp(0, i, 0x141, 0xF, 0xF, false);
    return __int_as_float(i);
}

// ---------------- recurrent scan (R6 core; pack+store in next step's shadow) ----------------
__global__ __launch_bounds__(256) void scan_kernel(
    const float* __restrict__ z,    // [2][M][HID]
    const float* __restrict__ Whh,  // [2][HID][HID] for this layer
    uint_t* __restrict__ opk)       // [M][KPAD] packed bf16 hi | lo<<16
{
    const int dir = blockIdx.x >> 6;
    const int b   = blockIdx.x & 63;
    const int tid = threadIdx.x;
    const int w   = tid >> 6;
    const int lane= tid & 63;
    const int q   = lane & 3;
    const int b2  = (lane >> 2) & 1;
    const int ks  = q | (b2 << 2);
    const int slot= (lane >> 3) + 8 * w;
    const bool active = (slot < 25);
    const int slotc = active ? slot : 24;
    const int jout = 4 * slotc + q;
    const bool writer = active && (b2 == 0);
    const int kb = 12 * ks;

    __shared__ float h_lds[2][112];
    for (int i = tid; i < 224; i += 256) (&h_lds[0][0])[i] = 0.f;

    float w4[4][16];
    #pragma unroll
    for (int r = 0; r < 4; ++r) {
        const float* wr = Whh + ((size_t)dir * HID + 4 * slotc + r) * HID + kb;
        #pragma unroll
        for (int i = 0; i < 4; ++i) {
            float4 v = *(const float4*)(wr + 4 * i);
            w4[r][4*i+0] = v.x; w4[r][4*i+1] = v.y;
            w4[r][4*i+2] = v.z; w4[r][4*i+3] = v.w;
        }
        if (ks > 0) {
            w4[r][0] = 0.f; w4[r][1] = 0.f; w4[r][2] = 0.f; w4[r][3] = 0.f;
        }
    }
    __syncthreads();

    const ptrdiff_t zstride = BATCH * HID;
    const ptrdiff_t ostride = BATCH * KPAD;     // uint units
    const int t0 = dir ? (T_LEN - 1) : 0;
    const ptrdiff_t zstep = dir ? -zstride : zstride;
    const ptrdiff_t ostep = dir ? -ostride : ostride;
    const ptrdiff_t zstep2 = 2 * zstep, zstep3 = 3 * zstep, zstep4 = 4 * zstep;

    const float* zp = z + (size_t)dir * M_TOT * HID + (size_t)b * HID + jout
                        + (ptrdiff_t)t0 * zstride;
    uint_t* op = opk + ((size_t)t0 * BATCH + b) * KPAD + dir * HID + jout;

    float zr0 = zp[0];
    float zr1 = zp[zstep];
    float zr2 = zp[zstep2];
    float zr3 = zp[zstep3];
    const float* zpf = zp + zstep4;

// Step: dot + DPP reduce + tanh + ds_write BEFORE the barrier; the packed
// global store (fire-and-forget) AFTER the barrier, overlapping the next
// step's independent LDS reads. RTZ hi split (lo absorbs the error).
#define RNN_STEP(ZREG, DO_PF, PFOFF, RD, WRB)                           \
  do {                                                                  \
    const float zin = ZREG;                                             \
    if (DO_PF) ZREG = *(zpf + (PFOFF));                                 \
    const float4* hp = (const float4*)((RD) + kb);                      \
    float a0 = 0.f, a1 = 0.f, a2 = 0.f, a3 = 0.f;                       \
    _Pragma("unroll")                                                   \
    for (int i = 0; i < 4; ++i) {                                       \
      float4 hv = hp[i];                                                \
      a0 += w4[0][4*i+0] * hv.x; a0 += w4[0][4*i+1] * hv.y;             \
      a0 += w4[0][4*i+2] * hv.z; a0 += w4[0][4*i+3] * hv.w;             \
      a1 += w4[1][4*i+0] * hv.x; a1 += w4[1][4*i+1] * hv.y;             \
      a1 += w4[1][4*i+2] * hv.z; a1 += w4[1][4*i+3] * hv.w;             \
      a2 += w4[2][4*i+0] * hv.x; a2 += w4[2][4*i+1] * hv.y;             \
      a2 += w4[2][4*i+2] * hv.z; a2 += w4[2][4*i+3] * hv.w;             \
      a3 += w4[3][4*i+0] * hv.x; a3 += w4[3][4*i+1] * hv.y;             \
      a3 += w4[3][4*i+2] * hv.z; a3 += w4[3][4*i+3] * hv.w;             \
    }                                                                   \
    float t0_ = a0 + dpp_hmir(a0);                                      \
    float t1_ = a1 + dpp_hmir(a1);                                      \
    float t2_ = a2 + dpp_hmir(a2);                                      \
    float t3_ = a3 + dpp_hmir(a3);                                      \
    float k01 = (q & 1) ? t1_ : t0_;                                    \
    float s01s = (q & 1) ? t0_ : t1_;                                   \
    float s01 = k01 + dpp_qxor1(s01s);                                  \
    float k23 = (q & 1) ? t3_ : t2_;                                    \
    float s23s = (q & 1) ? t2_ : t3_;                                   \
    float s23 = k23 + dpp_qxor1(s23s);                                  \
    float kf = (q & 2) ? s23 : s01;                                     \
    float sf = (q & 2) ? s01 : s23;                                     \
    float tot = kf + dpp_qxor2(sf);                                     \
    float xin = zin + tot;                                              \
    float ax = fabsf(xin);                                              \
    float e = __expf(2.f * ax);                                         \
    float r = 1.f - 2.f / (e + 1.f);                                    \
    float val = copysignf(r, xin);                                      \
    if (writer) (WRB)[jout] = val;                                      \
    asm volatile("s_waitcnt lgkmcnt(0)" ::: "memory");                  \
    __builtin_amdgcn_sched_barrier(0);                                  \
    __builtin_amdgcn_s_barrier();                                       \
    __builtin_amdgcn_sched_barrier(0);                                  \
    if (writer) *op = pack_hilo(val);   /* shadow of next step */       \
    op += ostep;                                                        \
  } while (0)

    float* const h0 = &h_lds[0][0];
    float* const h1 = &h_lds[1][0];

    for (int g = 0; g < (T_LEN / 4) - 1; ++g) {
        RNN_STEP(zr0, 1, 0,      h0, h1);
        RNN_STEP(zr1, 1, zstep,  h1, h0);
        RNN_STEP(zr2, 1, zstep2, h0, h1);
        RNN_STEP(zr3, 1, zstep3, h1, h0);
        zpf += zstep4;
    }
    RNN_STEP(zr0, 0, 0, h0, h1);
    RNN_STEP(zr1, 0, 0, h1, h0);
    RNN_STEP(zr2, 0, 0, h0, h1);
    RNN_STEP(zr3, 0, 0, h1, h0);

#undef RNN_STEP
}

// ---------------- output projection (reads packed) ----------------
__global__ __launch_bounds__(256) void outproj_kernel(
    const uint_t* __restrict__ hpk,
    const float* __restrict__ Wout, const float* __restrict__ bout,
    float* __restrict__ y)
{
    const int gid = blockIdx.x * 256 + threadIdx.x;
    const int wid = gid >> 6;
    const int lane = threadIdx.x & 63;
    if (wid >= M_TOT) return;
    const uint_t* rp = hpk + (size_t)wid * KPAD;
    float acc = 0.f;
    for (int k = lane; k < 200; k += 64) {
        uint_t p = rp[k];
        float hv = __uint_as_float(p << 16)
                 + __uint_as_float(p & 0xFFFF0000u);
        acc += hv * Wout[k];
    }
    #pragma unroll
    for (int off = 32; off > 0; off >>= 1) acc += __shfl_xor(acc, off);
    if (lane == 0) y[wid] = 1.f / (1.f + __expf(-(acc + bout[0])));
}

extern "C" void kernel_launch(void* const* d_in, const int* in_sizes, int n_in,
                              void* d_out, int out_size, void* d_ws, size_t ws_size,
                              hipStream_t stream)
{
    const float* x     = (const float*)d_in[0];
    const float* W_ih0 = (const float*)d_in[1];
    const float* W_ih  = (const float*)d_in[2];
    const float* W_hh  = (const float*)d_in[3];
    const float* b_ih  = (const float*)d_in[4];
    const float* b_hh  = (const float*)d_in[5];
    const float* W_out = (const float*)d_in[6];
    const float* b_out = (const float*)d_in[7];
    float* y = (float*)d_out;

    float* z = (float*)d_ws;                                  // 2*M*100 f32
    uint_t* pkA = (uint_t*)(z + (size_t)2 * M_TOT * HID);     // [M][KPAD] u32
    uint_t* pkB = pkA + (size_t)M_TOT * KPAD;
    ushort_t* wbuf = (ushort_t*)(pkB + (size_t)M_TOT * KPAD); // 9 x 2 planes
    ushort_t* w0buf = wbuf + (size_t)9 * 2 * WPLANE;          // 2 planes [208][128]
    uint_t* xpk = pkB;    // aliases pkB: consumed by mfma0 before pkB's first use

    wsplit_all_kernel<<<(9 * WPLANE + 255) / 256, 256, 0, stream>>>(W_ih, wbuf);
    wsplit0_kernel<<<(W0PLANE + 255) / 256, 256, 0, stream>>>(W_ih0, w0buf);
    xsplit_kernel<<<(M_TOT * KP0) / 256, 256, 0, stream>>>(x, xpk);

    // layer 0: MFMA GEMM (packed x, K=128) -> z ; then free pkB for reuse
    ingemm_mfma_kernel<4, KP0><<<512, 256, 0, stream>>>(
        xpk, w0buf, w0buf + W0PLANE, b_ih, b_hh, z);
    zeropad_kernel<<<(M_TOT * 24 + 255) / 256, 256, 0, stream>>>(pkA, pkB);
    scan_kernel<<<128, 256, 0, stream>>>(z, W_hh, pkA);

    for (int l = 1; l < 10; ++l) {
        const uint_t* in = (l & 1) ? pkA : pkB;
        uint_t* out      = (l & 1) ? pkB : pkA;
        const ushort_t* whi = wbuf + (size_t)(l - 1) * 2 * WPLANE;
        ingemm_mfma_kernel<7, KPAD><<<512, 256, 0, stream>>>(
            in, whi, whi + WPLANE, b_ih + l * 200, b_hh + l * 200, z);
        scan_kernel<<<128, 256, 0, stream>>>(
            z, W_hh + (size_t)l * 2 * HID * HID, out);
    }
    // layer 9 (odd) wrote pkB
    outproj_kernel<<<M_TOT / 4, 256, 0, stream>>>(pkB, W_out, b_out, y);
}

// Round 12
// 2029.847 us; speedup vs baseline: 1.0554x; 1.0554x over previous
//
#include <hip/hip_runtime.h>
#include <math.h>

// Bidirectional 10-layer tanh RNN, T=512 B=64 H=100, + sigmoid head.
// R12: the hi/lo bf16 split is moved OUT of the serial scan entirely.
// Scan stores plain fp32 h (store path instruction-identical to the proven
// R6 kernel, 173.6us) into [M][224]; the MFMA ingemm loads A-fragments as
// fp32 (same bytes as packed u32) and does the RNE hi/lo split once at
// fragment setup (~340 one-time VALU per wave, amortized over 273 MFMAs).
// Layer 0 reverted to the proven fp32 GEMM (R11's MFMA L0 swap measured
// net-zero). W planes stay pre-split. outproj reads fp32 directly.

#define T_LEN 512
#define BATCH 64
#define HID   100
#define M_TOT (T_LEN * BATCH)   // 32768
#define KPAD  224               // 7 chunks of 32 (layers 1..9)
#define NPAD  208               // 13 tiles of 16
#define WPLANE (NPAD * KPAD)    // 46592

typedef unsigned short ushort_t;
typedef unsigned int   uint_t;
typedef __attribute__((ext_vector_type(8))) __bf16 bf16x8;
typedef __attribute__((ext_vector_type(4))) float f32x4;

// ---------------- helpers: bf16 RNE split ----------------
__device__ __forceinline__ unsigned bf16_rne(float v) {
    unsigned u = __float_as_uint(v);
    return (u + 0x7FFFu + ((u >> 16) & 1u)) >> 16;
}

// ---------------- fp32 input GEMM, layer 0 only (R7 structure, proven) ----------------
__global__ __launch_bounds__(256) void ingemm_kernel(
    const float* __restrict__ In, const float* __restrict__ W,
    const float* __restrict__ bih, const float* __restrict__ bhh,
    float* __restrict__ z, int K)
{
    __shared__ float As[16][132];
    __shared__ float Bs[16][68];
    const int tid = threadIdx.x;
    const int m0 = blockIdx.x * 128;
    const int n0 = blockIdx.y * 64;
    const int tx = tid & 15, ty = tid >> 4;
    const int lm = tid >> 2;
    const int lk = (tid & 3) << 2;

    float acc[8][4];
    #pragma unroll
    for (int i = 0; i < 8; ++i)
        #pragma unroll
        for (int j = 0; j < 4; ++j) acc[i][j] = 0.f;

    for (int k0 = 0; k0 < K; k0 += 16) {
        #pragma unroll
        for (int rep = 0; rep < 2; ++rep) {
            float4 av = make_float4(0.f,0.f,0.f,0.f);
            const int row = lm + 64 * rep;
            if (k0 + lk < K)
                av = *(const float4*)(In + (size_t)(m0 + row) * K + k0 + lk);
            As[lk+0][row]=av.x; As[lk+1][row]=av.y;
            As[lk+2][row]=av.z; As[lk+3][row]=av.w;
        }
        {
            float4 bv = make_float4(0.f,0.f,0.f,0.f);
            const int nrow = n0 + lm;
            if (nrow < 200 && k0 + lk < K)
                bv = *(const float4*)(W + (size_t)nrow * K + k0 + lk);
            Bs[lk+0][lm]=bv.x; Bs[lk+1][lm]=bv.y;
            Bs[lk+2][lm]=bv.z; Bs[lk+3][lm]=bv.w;
        }
        __syncthreads();
        #pragma unroll
        for (int kk = 0; kk < 16; ++kk) {
            float4 alo = *(const float4*)&As[kk][ty << 2];
            float4 ahi = *(const float4*)&As[kk][64 + (ty << 2)];
            float4 b4  = *(const float4*)&Bs[kk][tx << 2];
            float a[8] = {alo.x, alo.y, alo.z, alo.w,
                          ahi.x, ahi.y, ahi.z, ahi.w};
            float b[4] = {b4.x, b4.y, b4.z, b4.w};
            #pragma unroll
            for (int i = 0; i < 8; ++i)
                #pragma unroll
                for (int j = 0; j < 4; ++j)
                    acc[i][j] += a[i] * b[j];
        }
        __syncthreads();
    }
    #pragma unroll
    for (int i = 0; i < 8; ++i) {
        const int m = m0 + ((i < 4) ? ((ty << 2) + i) : (64 + (ty << 2) + (i - 4)));
        #pragma unroll
        for (int j = 0; j < 4; ++j) {
            const int n = n0 + (tx << 2) + j;
            if (n < 200) {
                const int dir = (n >= 100) ? 1 : 0;
                const int h = n - dir * 100;
                z[(size_t)dir * M_TOT * HID + (size_t)m * HID + h] =
                    acc[i][j] + bih[n] + bhh[n];
            }
        }
    }
}

// zero the pad columns (k = 200..223) of the 2 fp32 ping-pong arrays
__global__ __launch_bounds__(256) void zeropad_kernel(float* a, float* b)
{
    int i = blockIdx.x * 256 + threadIdx.x;      // M*24
    if (i >= M_TOT * 24) return;
    size_t off = (size_t)(i / 24) * KPAD + 200 + (i % 24);
    a[off] = 0.f; b[off] = 0.f;
}

// split ALL 9 layers' W_ih (fp32 [200][200]) into zero-padded bf16 hi/lo
// planes: wbuf + l*2*WPLANE = hi plane, + WPLANE = lo plane.
__global__ __launch_bounds__(256) void wsplit_all_kernel(
    const float* __restrict__ W_ih, ushort_t* __restrict__ wbuf)
{
    int i = blockIdx.x * 256 + threadIdx.x;      // 9*WPLANE
    if (i >= 9 * WPLANE) return;
    int l = i / WPLANE;
    int r = i - l * WPLANE;
    int n = r / KPAD, k = r - (r / KPAD) * KPAD;
    const float* W = W_ih + (size_t)l * 2 * 100 * 200;
    float v = (n < 200 && k < 200) ? W[n * 200 + k] : 0.f;
    unsigned hr = bf16_rne(v);
    float hv = __uint_as_float(hr << 16);
    unsigned lr = bf16_rne(v - hv);
    ushort_t* whi = wbuf + (size_t)l * 2 * WPLANE;
    whi[r] = (ushort_t)hr;
    whi[WPLANE + r] = (ushort_t)lr;
}

// ---------------- MFMA input GEMM, layers 1..9 ----------------
// In = fp32 h [M][KPAD] (pads zero); W = pre-split hi/lo planes [NPAD][KPAD].
// One wave per 16-row m-tile; A fragments loaded fp32 and RNE-split at setup
// (one-time); loop 13 n-tiles x 7 k-chunks x 3 MFMA (hh, hl, lh).
// Fragment layout: lane -> (row=lane&15, k=8*(lane>>4)+b);
// D: col=lane&15, row=(lane>>4)*4+reg.
__global__ __launch_bounds__(256) void ingemm_mfma_kernel(
    const float* __restrict__ in_f,
    const ushort_t* __restrict__ w_hi,  const ushort_t* __restrict__ w_lo,
    const float* __restrict__ bih, const float* __restrict__ bhh,
    float* __restrict__ z)
{
    const int wv   = threadIdx.x >> 6;
    const int lane = threadIdx.x & 63;
    const int mt   = blockIdx.x * 4 + wv;     // m-tile 0..2047
    const int m0   = mt * 16;
    const int r16  = lane & 15;
    const int kg   = lane >> 4;
    const int kof  = kg * 8;

    // A fragments: 7 k-chunks x {hi, lo}, RNE-split from fp32 (one-time)
    bf16x8 ah[7], al[7];
    const float* arp = in_f + (size_t)(m0 + r16) * KPAD + kof;
    #pragma unroll
    for (int c = 0; c < 7; ++c) {
        float4 v0 = *(const float4*)(arp + 32 * c);
        float4 v1 = *(const float4*)(arp + 32 * c + 4);
        float vv[8] = {v0.x, v0.y, v0.z, v0.w, v1.x, v1.y, v1.z, v1.w};
        union { bf16x8 v; ushort_t u[8]; } hh, ll;
        #pragma unroll
        for (int i = 0; i < 8; ++i) {
            unsigned hr = bf16_rne(vv[i]);
            hh.u[i] = (ushort_t)hr;
            ll.u[i] = (ushort_t)bf16_rne(vv[i] - __uint_as_float(hr << 16));
        }
        ah[c] = hh.v; al[c] = ll.v;
    }

    for (int nt = 0; nt < 13; ++nt) {
        const int n0 = nt * 16;
        const ushort_t* brh = w_hi + (size_t)(n0 + r16) * KPAD + kof;
        const ushort_t* brl = w_lo + (size_t)(n0 + r16) * KPAD + kof;
        f32x4 acc = {0.f, 0.f, 0.f, 0.f};
        #pragma unroll
        for (int c = 0; c < 7; ++c) {
            bf16x8 bh = *(const bf16x8*)(brh + 32 * c);
            bf16x8 bl = *(const bf16x8*)(brl + 32 * c);
            acc = __builtin_amdgcn_mfma_f32_16x16x32_bf16(ah[c], bh, acc, 0, 0, 0);
            acc = __builtin_amdgcn_mfma_f32_16x16x32_bf16(ah[c], bl, acc, 0, 0, 0);
            acc = __builtin_amdgcn_mfma_f32_16x16x32_bf16(al[c], bh, acc, 0, 0, 0);
        }
        const int n = n0 + r16;
        if (n < 200) {
            const int dir = (n >= 100) ? 1 : 0;
            const int h = n - dir * 100;
            const float bias = bih[n] + bhh[n];
            #pragma unroll
            for (int r = 0; r < 4; ++r) {
                const int m = m0 + kg * 4 + r;
                z[(size_t)dir * M_TOT * HID + (size_t)m * HID + h] = acc[r] + bias;
            }
        }
    }
}

// DPP helpers — guaranteed VALU lane exchange (no LDS).
__device__ __forceinline__ float dpp_qxor1(float x) {
    int i = __float_as_int(x);
    i = __builtin_amdgcn_update_dpp(0, i, 0xB1, 0xF, 0xF, false);
    return __int_as_float(i);
}
__device__ __forceinline__ float dpp_qxor2(float x) {
    int i = __float_as_int(x);
    i = __builtin_amdgcn_update_dpp(0, i, 0x4E, 0xF, 0xF, false);
    return __int_as_float(i);
}
__device__ __forceinline__ float dpp_hmir(float x) {  // lane ^ 7
    int i = __float_as_int(x);
    i = __builtin_amdgcn_update_dpp(0, i, 0x141, 0xF, 0xF, false);
    return __int_as_float(i);
}

// ---------------- recurrent scan (R6 core exact; fp32 store, KPAD stride) ----------------
__global__ __launch_bounds__(256) void scan_kernel(
    const float* __restrict__ z,    // [2][M][HID]
    const float* __restrict__ Whh,  // [2][HID][HID] for this layer
    float* __restrict__ out)        // [M][KPAD] fp32 (pads pre-zeroed)
{
    const int dir = blockIdx.x >> 6;
    const int b   = blockIdx.x & 63;
    const int tid = threadIdx.x;
    const int w   = tid >> 6;
    const int lane= tid & 63;
    const int q   = lane & 3;
    const int b2  = (lane >> 2) & 1;
    const int ks  = q | (b2 << 2);
    const int slot= (lane >> 3) + 8 * w;
    const bool active = (slot < 25);
    const int slotc = active ? slot : 24;
    const int jout = 4 * slotc + q;
    const bool writer = active && (b2 == 0);
    const int kb = 12 * ks;

    __shared__ float h_lds[2][112];
    for (int i = tid; i < 224; i += 256) (&h_lds[0][0])[i] = 0.f;

    float w4[4][16];
    #pragma unroll
    for (int r = 0; r < 4; ++r) {
        const float* wr = Whh + ((size_t)dir * HID + 4 * slotc + r) * HID + kb;
        #pragma unroll
        for (int i = 0; i < 4; ++i) {
            float4 v = *(const float4*)(wr + 4 * i);
            w4[r][4*i+0] = v.x; w4[r][4*i+1] = v.y;
            w4[r][4*i+2] = v.z; w4[r][4*i+3] = v.w;
        }
        if (ks > 0) {
            w4[r][0] = 0.f; w4[r][1] = 0.f; w4[r][2] = 0.f; w4[r][3] = 0.f;
        }
    }
    __syncthreads();

    const ptrdiff_t zstride = BATCH * HID;
    const ptrdiff_t ostride = BATCH * KPAD;
    const int t0 = dir ? (T_LEN - 1) : 0;
    const ptrdiff_t zstep = dir ? -zstride : zstride;
    const ptrdiff_t ostep = dir ? -ostride : ostride;
    const ptrdiff_t zstep2 = 2 * zstep, zstep3 = 3 * zstep, zstep4 = 4 * zstep;

    const float* zp = z + (size_t)dir * M_TOT * HID + (size_t)b * HID + jout
                        + (ptrdiff_t)t0 * zstride;
    float* op = out + ((size_t)t0 * BATCH + b) * KPAD + dir * HID + jout;

    float zr0 = zp[0];
    float zr1 = zp[zstep];
    float zr2 = zp[zstep2];
    float zr3 = zp[zstep3];
    const float* zpf = zp + zstep4;

// One step (R6-proven shape): 4 b128 LDS reads, 64 FMAs, 3-hop all-DPP
// reduce, tanh, fp32 ds_write + fp32 global store BEFORE the lgkm drain.
#define RNN_STEP(ZREG, DO_PF, PFOFF, RD, WRB)                           \
  do {                                                                  \
    const float zin = ZREG;                                             \
    if (DO_PF) ZREG = *(zpf + (PFOFF));                                 \
    const float4* hp = (const float4*)((RD) + kb);                      \
    float a0 = 0.f, a1 = 0.f, a2 = 0.f, a3 = 0.f;                       \
    _Pragma("unroll")                                                   \
    for (int i = 0; i < 4; ++i) {                                       \
      float4 hv = hp[i];                                                \
      a0 += w4[0][4*i+0] * hv.x; a0 += w4[0][4*i+1] * hv.y;             \
      a0 += w4[0][4*i+2] * hv.z; a0 += w4[0][4*i+3] * hv.w;             \
      a1 += w4[1][4*i+0] * hv.x; a1 += w4[1][4*i+1] * hv.y;             \
      a1 += w4[1][4*i+2] * hv.z; a1 += w4[1][4*i+3] * hv.w;             \
      a2 += w4[2][4*i+0] * hv.x; a2 += w4[2][4*i+1] * hv.y;             \
      a2 += w4[2][4*i+2] * hv.z; a2 += w4[2][4*i+3] * hv.w;             \
      a3 += w4[3][4*i+0] * hv.x; a3 += w4[3][4*i+1] * hv.y;             \
      a3 += w4[3][4*i+2] * hv.z; a3 += w4[3][4*i+3] * hv.w;             \
    }                                                                   \
    float t0_ = a0 + dpp_hmir(a0);                                      \
    float t1_ = a1 + dpp_hmir(a1);                                      \
    float t2_ = a2 + dpp_hmir(a2);                                      \
    float t3_ = a3 + dpp_hmir(a3);                                      \
    float k01 = (q & 1) ? t1_ : t0_;                                    \
    float s01s = (q & 1) ? t0_ : t1_;                                   \
    float s01 = k01 + dpp_qxor1(s01s);                                  \
    float k23 = (q & 1) ? t3_ : t2_;                                    \
    float s23s = (q & 1) ? t2_ : t3_;                                   \
    float s23 = k23 + dpp_qxor1(s23s);                                  \
    float kf = (q & 2) ? s23 : s01;                                     \
    float sf = (q & 2) ? s01 : s23;                                     \
    float tot = kf + dpp_qxor2(sf);                                     \
    float xin = zin + tot;                                              \
    float ax = fabsf(xin);                                              \
    float e = __expf(2.f * ax);                                         \
    float r = 1.f - 2.f / (e + 1.f);                                    \
    float val = copysignf(r, xin);                                      \
    if (writer) {                                                       \
      (WRB)[jout] = val;                                                \
      *op = val;                                                        \
    }                                                                   \
    op += ostep;                                                        \
    asm volatile("s_waitcnt lgkmcnt(0)" ::: "memory");                  \
    __builtin_amdgcn_sched_barrier(0);                                  \
    __builtin_amdgcn_s_barrier();                                       \
    __builtin_amdgcn_sched_barrier(0);                                  \
  } while (0)

    float* const h0 = &h_lds[0][0];
    float* const h1 = &h_lds[1][0];

    for (int g = 0; g < (T_LEN / 4) - 1; ++g) {
        RNN_STEP(zr0, 1, 0,      h0, h1);
        RNN_STEP(zr1, 1, zstep,  h1, h0);
        RNN_STEP(zr2, 1, zstep2, h0, h1);
        RNN_STEP(zr3, 1, zstep3, h1, h0);
        zpf += zstep4;
    }
    RNN_STEP(zr0, 0, 0, h0, h1);
    RNN_STEP(zr1, 0, 0, h1, h0);
    RNN_STEP(zr2, 0, 0, h0, h1);
    RNN_STEP(zr3, 0, 0, h1, h0);

#undef RNN_STEP
}

// ---------------- output projection (fp32 [M][KPAD]) ----------------
__global__ __launch_bounds__(256) void outproj_kernel(
    const float* __restrict__ h,
    const float* __restrict__ Wout, const float* __restrict__ bout,
    float* __restrict__ y)
{
    const int gid = blockIdx.x * 256 + threadIdx.x;
    const int wid = gid >> 6;
    const int lane = threadIdx.x & 63;
    if (wid >= M_TOT) return;
    const float* row = h + (size_t)wid * KPAD;
    float acc = 0.f;
    for (int k = lane; k < 200; k += 64) acc += row[k] * Wout[k];
    #pragma unroll
    for (int off = 32; off > 0; off >>= 1) acc += __shfl_xor(acc, off);
    if (lane == 0) y[wid] = 1.f / (1.f + __expf(-(acc + bout[0])));
}

extern "C" void kernel_launch(void* const* d_in, const int* in_sizes, int n_in,
                              void* d_out, int out_size, void* d_ws, size_t ws_size,
                              hipStream_t stream)
{
    const float* x     = (const float*)d_in[0];
    const float* W_ih0 = (const float*)d_in[1];
    const float* W_ih  = (const float*)d_in[2];
    const float* W_hh  = (const float*)d_in[3];
    const float* b_ih  = (const float*)d_in[4];
    const float* b_hh  = (const float*)d_in[5];
    const float* W_out = (const float*)d_in[6];
    const float* b_out = (const float*)d_in[7];
    float* y = (float*)d_out;

    float* z  = (float*)d_ws;                              // 2*M*100 f32
    float* fA = z + (size_t)2 * M_TOT * HID;               // [M][KPAD] f32
    float* fB = fA + (size_t)M_TOT * KPAD;
    ushort_t* wbuf = (ushort_t*)(fB + (size_t)M_TOT * KPAD); // 9 x 2 planes

    wsplit_all_kernel<<<(9 * WPLANE + 255) / 256, 256, 0, stream>>>(W_ih, wbuf);
    zeropad_kernel<<<(M_TOT * 24 + 255) / 256, 256, 0, stream>>>(fA, fB);

    // layer 0: fp32 GEMM (x, K=100) -> z ; scan -> fA
    ingemm_kernel<<<dim3(M_TOT / 128, 4), 256, 0, stream>>>(
        x, W_ih0, b_ih, b_hh, z, 100);
    scan_kernel<<<128, 256, 0, stream>>>(z, W_hh, fA);

    for (int l = 1; l < 10; ++l) {
        const float* in = (l & 1) ? fA : fB;
        float* out      = (l & 1) ? fB : fA;
        const ushort_t* whi = wbuf + (size_t)(l - 1) * 2 * WPLANE;
        ingemm_mfma_kernel<<<512, 256, 0, stream>>>(
            in, whi, whi + WPLANE, b_ih + l * 200, b_hh + l * 200, z);
        scan_kernel<<<128, 256, 0, stream>>>(
            z, W_hh + (size_t)l * 2 * HID * HID, out);
    }
    // layer 9 (odd) wrote fB
    outproj_kernel<<<M_TOT / 4, 256, 0, stream>>>(fB, W_out, b_out, y);
}